// Round 23
// baseline (183.290 us; speedup 1.0000x reference)
//
#include <hip/hip_runtime.h>
#include <hip/hip_fp16.h>
#include <cstdint>

typedef __attribute__((ext_vector_type(8))) _Float16 f16x8;
typedef __attribute__((ext_vector_type(4))) float f32x4;
typedef __attribute__((ext_vector_type(16))) float f32x16;

__device__ __forceinline__ f16x8 cvt8(float4 x, float4 y) {
    f16x8 r;
    r[0] = (_Float16)x.x; r[1] = (_Float16)x.y; r[2] = (_Float16)x.z; r[3] = (_Float16)x.w;
    r[4] = (_Float16)y.x; r[5] = (_Float16)y.y; r[6] = (_Float16)y.z; r[7] = (_Float16)y.w;
    return r;
}

__device__ __forceinline__ f16x8 relu8(f16x8 v) {
    f16x8 z = {};
    return __builtin_elementwise_max(v, z);   // v_pk_max_f16
}

// =============== prep1: ALL prep in one kernel (verbatim round 20 — PASSED) ===============
__global__ __launch_bounds__(256, 2)
void prep1(const float* __restrict__ query,
           const float* __restrict__ prot,
           const float* __restrict__ W1,
           const float* __restrict__ b1,
           const float* __restrict__ W2,
           const float* __restrict__ b2,
           _Float16* __restrict__ qh16,
           float* __restrict__ sqp,
           _Float16* __restrict__ phpk,
           f16x8* __restrict__ w2p,
           float* __restrict__ Gm,
           float* __restrict__ q2) {
    __shared__ _Float16 Bls[64][280];   // [col_local][k], 280 = 16B-aligned rows, 2 lanes/bank
    int b = blockIdx.x, t = threadIdx.x;

    if (b < 200) {
        int mode, row0, col0;
        if (b < 128)      { mode = 0; row0 = (b >> 2) * 64;         col0 = (b & 3) * 64; }
        else if (b < 192) { mode = 1; row0 = ((b - 128) >> 1) * 64; col0 = ((b - 128) & 1) * 64; }
        else              { mode = 2; row0 = ((b - 192) >> 2) * 64; col0 = ((b - 192) & 3) * 64; }
        const float* Asrc = (mode == 2) ? prot : query;

        if (mode != 1) {
            int woff = (mode == 2) ? 256 : 0;
            int rr = t >> 4, c4 = (t & 15) * 4;
            for (int rt = 0; rt < 4; ++rt) {
                #pragma unroll
                for (int it = 0; it < 4; ++it) {
                    int k = rt * 64 + it * 16 + rr;
                    float4 v = *(const float4*)(W1 + (woff + k) * 256 + col0 + c4);
                    Bls[c4 + 0][k] = (_Float16)v.x;
                    Bls[c4 + 1][k] = (_Float16)v.y;
                    Bls[c4 + 2][k] = (_Float16)v.z;
                    Bls[c4 + 3][k] = (_Float16)v.w;
                }
            }
            __syncthreads();
        }

        int w = t >> 6, l = t & 63, l15 = l & 15, l4 = l >> 4;
        f32x4 acc[4];
        #pragma unroll
        for (int nt = 0; nt < 4; ++nt) acc[nt] = (f32x4){0.f, 0.f, 0.f, 0.f};

        for (int ks = 0; ks < 8; ++ks) {
            int row = row0 + w * 16 + l15;
            const float* ap = Asrc + row * 256 + ks * 32 + l4 * 8;
            f16x8 af = cvt8(*(const float4*)ap, *(const float4*)(ap + 4));
            f16x8 bf[4];
            #pragma unroll
            for (int nt = 0; nt < 4; ++nt) {
                if (mode == 1) {
                    int col = col0 + nt * 16 + l15;
                    const float* bp = prot + col * 256 + ks * 32 + l4 * 8;
                    bf[nt] = cvt8(*(const float4*)bp, *(const float4*)(bp + 4));
                } else {
                    bf[nt] = *(const f16x8*)(&Bls[nt * 16 + l15][ks * 32 + l4 * 8]);
                }
            }
            #pragma unroll
            for (int nt = 0; nt < 4; ++nt)
                acc[nt] = __builtin_amdgcn_mfma_f32_16x16x32_f16(af, bf[nt], acc[nt], 0, 0, 0);
        }
        #pragma unroll
        for (int nt = 0; nt < 4; ++nt)
            #pragma unroll
            for (int j = 0; j < 4; ++j) {
                int row = row0 + w * 16 + l4 * 4 + j;
                int col = col0 + nt * 16 + l15;
                float v = acc[nt][j];
                if (mode == 0) {
                    _Float16 v16 = (_Float16)v;
                    __builtin_nontemporal_store(v16, &qh16[row * 256 + col]);
                } else if (mode == 1) {
                    __builtin_nontemporal_store(v, &sqp[row * 128 + col]);
                } else {
                    _Float16 v16 = (_Float16)(v + b1[col]);
                    __builtin_nontemporal_store(v16,
                        &phpk[(((col >> 4) * 2 + ((col >> 3) & 1)) * 128 + row) * 8 + (col & 7)]);
                }
            }
    } else if (b < 217) {
        int chunk = (b - 200) * 256 + t;          // 0..4351
        int ks = chunk >> 8, h = (chunk >> 7) & 1, c = chunk & 127;
        f16x8 o = {};
        if (ks < 16) {
            #pragma unroll
            for (int j = 0; j < 8; ++j)
                o[j] = (_Float16)W2[(ks * 16 + h * 8 + j) * 128 + c];
        } else if (h == 0) {
            o[0] = (_Float16)b2[c];
        }
        __builtin_nontemporal_store(o, &w2p[chunk]);
    } else if (b < 249) {
        int pid = (b - 217) * 32 + (t >> 3), l8 = t & 7;
        int c = pid >> 6, k = (pid >> 3) & 7, kp = pid & 7;
        const float4* pa = (const float4*)(prot + (c * 8 + k) * 256 + l8 * 32);
        const float4* pb = (const float4*)(prot + (c * 8 + kp) * 256 + l8 * 32);
        float s = 0.f;
        #pragma unroll
        for (int i = 0; i < 8; ++i) {
            float4 x = pa[i], y = pb[i];
            s += x.x * y.x + x.y * y.y + x.z * y.z + x.w * y.w;
        }
        s += __shfl_xor(s, 1); s += __shfl_xor(s, 2); s += __shfl_xor(s, 4);
        if (l8 == 0) __builtin_nontemporal_store(s, &Gm[pid]);
    } else {
        int m = (b - 249) * 32 + (t >> 3), l8 = t & 7;
        const float4* qp = (const float4*)(query + m * 256 + l8 * 32);
        float s = 0.f;
        #pragma unroll
        for (int i = 0; i < 8; ++i) {
            float4 x = qp[i];
            s += x.x * x.x + x.y * x.y + x.z * x.z + x.w * x.w;
        }
        s += __shfl_xor(s, 1); s += __shfl_xor(s, 2); s += __shfl_xor(s, 4);
        if (l8 == 0) __builtin_nontemporal_store(s, &q2[m]);
    }
}

// =============== fused9: m-split + act[16] in regs (built ONCE) + sequential col-strips =====
// 512 thr = 8 waves; wave = ONE m x 32-ck strip x sequential 4 col-strips.
// act[16] (64 VGPR) built once per m (chip VALU 3.4us); acc = aE/aO split-K pair (32 AGPR)
// reused across strips -> per-wave regs ~140. W2+ph in LDS (80 KB); 8 waves = 2 waves/SIMD.
// Epilogue wave-local (fused8 form, verified). grid = 512 (4 cks x 128 mg of 16 m, 2 passes).
__global__ __launch_bounds__(512, 1)
void fused9(const _Float16* __restrict__ qh16,
            const uint4* __restrict__ phpk,
            const uint4* __restrict__ w2p,
            const float* __restrict__ sqp,
            const float* __restrict__ q2,
            const float* __restrict__ Gm,
            const float* __restrict__ W3,
            const float* __restrict__ b2,
            float* __restrict__ out) {
    __shared__ uint4 w2l[4096];               // W2: [ks 16][h 2][col 128] x 16B = 64 KB
    __shared__ uint4 phl[1024];               // ph strip: [ks2h 32][ckl 32] = 16 KB
    __shared__ _Float16 qlds[16 * 256];       // 16 q rows, 8 KB = 512 uint4
    __shared__ float sql[16 * 32];            // sqp strip [mloc][ckl], 2 KB
    __shared__ float gml[256];                // Gm strip (4 classes x 64), 1 KB
    __shared__ float w3l[128];
    __shared__ float b2l[128];
    __shared__ float q2l[16];

    int t = threadIdx.x;
    int wid = t >> 6, l = t & 63;
    int lk = l & 31, h = l >> 5;
    int cks = blockIdx.x & 3;                 // which 32-ck strip
    int mg = blockIdx.x >> 2;                 // 0..127
    int m0 = mg * 16;

    // stage: W2 (8 uint4/thr), ph strip (2/thr), 16 q rows (1/thr), sql/gml/w3/b2/q2
    #pragma unroll
    for (int i = 0; i < 8; ++i) w2l[t + i * 512] = w2p[t + i * 512];
    #pragma unroll
    for (int i = 0; i < 2; ++i) {
        int j = t + i * 512;
        phl[j] = phpk[(j >> 5) * 128 + cks * 32 + (j & 31)];
    }
    ((uint4*)qlds)[t] = ((const uint4*)(qh16 + m0 * 256))[t];
    if (t < 512) {
        int r0 = t >> 5, c0 = t & 31;
        if (t < 512) sql[t & 511] = 0.f;      // placeholder overwritten below
        if (r0 < 16) sql[r0 * 32 + c0] = sqp[(m0 + r0) * 128 + cks * 32 + c0];
    }
    if (t < 256) gml[t] = Gm[cks * 256 + t];
    if (t < 128) { w3l[t] = W3[t]; b2l[t] = b2[t]; }
    if (t < 16) q2l[t] = q2[m0 + t];

    __syncthreads();

    const _Float16* w2lh = (const _Float16*)w2l;
    const f16x8* phlh = (const f16x8*)phl;

    for (int pass = 0; pass < 2; ++pass) {
        int mloc = pass * 8 + wid;            // each wave owns one m per pass
        int m = m0 + mloc;
        const _Float16* qr = qlds + mloc * 256 + h * 8;

        // build act[16] ONCE (ph from LDS, no reg storage for ph)
        f16x8 act[16];
        f16x8 qv[2];
        qv[0] = *(const f16x8*)(qr);
        qv[1] = *(const f16x8*)(qr + 16);
        #pragma unroll
        for (int ks = 0; ks < 16; ++ks) {
            f16x8 phf = phlh[(ks * 2 + h) * 32 + lk];
            act[ks] = relu8(qv[ks & 1] + phf);
            if (ks < 14)
                qv[ks & 1] = *(const f16x8*)(qr + (ks + 2) * 16);
        }

        // 4 sequential col-strips, acc pair reused (split-K parity chains)
        float sc = 0.f;
        #pragma unroll
        for (int s = 0; s < 4; ++s) {
            f32x16 aE = {}, aO = {};
            #pragma unroll
            for (int ks = 0; ks < 16; ks += 2) {
                f16x8 bE = *(const f16x8*)(w2lh + (((ks + 0) * 2 + h) * 128 + s * 32 + lk) * 8);
                f16x8 bO = *(const f16x8*)(w2lh + (((ks + 1) * 2 + h) * 128 + s * 32 + lk) * 8);
                aE = __builtin_amdgcn_mfma_f32_32x32x16_f16(bE, act[ks + 0], aE, 0, 0, 0);
                aO = __builtin_amdgcn_mfma_f32_32x32x16_f16(bO, act[ks + 1], aO, 0, 0, 0);
            }
            #pragma unroll
            for (int r = 0; r < 16; ++r) {
                int ci = s * 32 + (r & 3) + 8 * (r >> 2) + 4 * h;
                sc = fmaf(fmaxf(aE[r] + aO[r] + b2l[ci], 0.f), w3l[ci], sc);
            }
        }
        sc += __shfl_xor(sc, 32);

        // softmax over K=8 within 8-lane group (wave-local)
        float mx = sc;
        mx = fmaxf(mx, __shfl_xor(mx, 1));
        mx = fmaxf(mx, __shfl_xor(mx, 2));
        mx = fmaxf(mx, __shfl_xor(mx, 4));
        float e = __expf(sc - mx);
        float den = e;
        den += __shfl_xor(den, 1); den += __shfl_xor(den, 2); den += __shfl_xor(den, 4);
        float a = e / den;

        // Gram-expanded distance (wave-local, all operands in LDS)
        int kk = l & 7, cgl = lk >> 3;
        float p2 = a * sql[mloc * 32 + lk];
        float p3 = 0.f;
        #pragma unroll
        for (int kq = 0; kq < 8; ++kq) {
            float ak = __shfl(a, (l & 56) | kq);
            p3 = fmaf(ak, gml[cgl * 64 + kq * 8 + kk], p3);
        }
        p3 *= a;
        float pr = p3 - 2.f * p2;
        pr += __shfl_xor(pr, 1); pr += __shfl_xor(pr, 2); pr += __shfl_xor(pr, 4);
        if (l < 32 && kk == 0)
            out[m * 16 + cks * 4 + cgl] = -sqrtf(fmaxf(q2l[mloc] + pr, 0.f));
    }
}

extern "C" void kernel_launch(void* const* d_in, const int* in_sizes, int n_in,
                              void* d_out, int out_size, void* d_ws, size_t ws_size,
                              hipStream_t stream) {
    const float* query = (const float*)d_in[0];
    const float* prot  = (const float*)d_in[1];
    const float* W1    = (const float*)d_in[2];
    const float* b1    = (const float*)d_in[3];
    const float* W2    = (const float*)d_in[4];
    const float* b2    = (const float*)d_in[5];
    const float* W3    = (const float*)d_in[6];
    // b3 (d_in[7]): constant pre-softmax shift -> softmax-invariant: unused.

    char* ws = (char*)d_ws;
    _Float16* qh16 = (_Float16*)(ws);                 // 2048*256*2 = 1048576
    f16x8*    w2p  = (f16x8*)(ws + 1048576);          // 4352*16    = 69632
    _Float16* phpk = (_Float16*)(ws + 1118208);       // 128*256*2  = 65536
    float*    sqp  = (float*)(ws + 1183744);          // 2048*128*4 = 1048576
    float*    q2   = (float*)(ws + 2232320);          // 2048*4     = 8192
    float*    Gm   = (float*)(ws + 2240512);          // 1024*4     = 4096
    float* out = (float*)d_out;

    prep1<<<313, 256, 0, stream>>>(query, prot, W1, b1, W2, b2,
                                   qh16, sqp, phpk, w2p, Gm, q2);
    fused9<<<512, 512, 0, stream>>>(qh16, (const uint4*)phpk, (const uint4*)w2p,
                                    sqp, q2, Gm, W3, b2, out);
}

// Round 24
// 39.292 us; speedup vs baseline: 4.6648x; 4.6648x over previous
//
#include <hip/hip_runtime.h>
#include <hip/hip_fp16.h>
#include <cstdint>

typedef __attribute__((ext_vector_type(8))) _Float16 f16x8;
typedef __attribute__((ext_vector_type(4))) float f32x4;
typedef __attribute__((ext_vector_type(16))) float f32x16;

__device__ __forceinline__ f16x8 cvt8(float4 x, float4 y) {
    f16x8 r;
    r[0] = (_Float16)x.x; r[1] = (_Float16)x.y; r[2] = (_Float16)x.z; r[3] = (_Float16)x.w;
    r[4] = (_Float16)y.x; r[5] = (_Float16)y.y; r[6] = (_Float16)y.z; r[7] = (_Float16)y.w;
    return r;
}

__device__ __forceinline__ f16x8 relu8(f16x8 v) {
    f16x8 z = {};
    return __builtin_elementwise_max(v, z);   // v_pk_max_f16
}

// =============== prep1: ALL prep in one kernel (verbatim round 16 — PASSED, best) ===============
__global__ __launch_bounds__(256, 2)
void prep1(const float* __restrict__ query,
           const float* __restrict__ prot,
           const float* __restrict__ W1,
           const float* __restrict__ b1,
           const float* __restrict__ W2,
           const float* __restrict__ b2,
           _Float16* __restrict__ qh16,
           float* __restrict__ sqp,
           _Float16* __restrict__ phpk,
           f16x8* __restrict__ w2p,
           float* __restrict__ Gm,
           float* __restrict__ q2) {
    __shared__ _Float16 Bls[64][280];   // [col_local][k], 280 = 16B-aligned rows, 2 lanes/bank
    int b = blockIdx.x, t = threadIdx.x;

    if (b < 200) {
        int mode, row0, col0;
        if (b < 128)      { mode = 0; row0 = (b >> 2) * 64;         col0 = (b & 3) * 64; }
        else if (b < 192) { mode = 1; row0 = ((b - 128) >> 1) * 64; col0 = ((b - 128) & 1) * 64; }
        else              { mode = 2; row0 = ((b - 192) >> 2) * 64; col0 = ((b - 192) & 3) * 64; }
        const float* Asrc = (mode == 2) ? prot : query;

        if (mode != 1) {
            int woff = (mode == 2) ? 256 : 0;
            int rr = t >> 4, c4 = (t & 15) * 4;
            for (int rt = 0; rt < 4; ++rt) {
                #pragma unroll
                for (int it = 0; it < 4; ++it) {
                    int k = rt * 64 + it * 16 + rr;
                    float4 v = *(const float4*)(W1 + (woff + k) * 256 + col0 + c4);
                    Bls[c4 + 0][k] = (_Float16)v.x;
                    Bls[c4 + 1][k] = (_Float16)v.y;
                    Bls[c4 + 2][k] = (_Float16)v.z;
                    Bls[c4 + 3][k] = (_Float16)v.w;
                }
            }
            __syncthreads();
        }

        int w = t >> 6, l = t & 63, l15 = l & 15, l4 = l >> 4;
        f32x4 acc[4];
        #pragma unroll
        for (int nt = 0; nt < 4; ++nt) acc[nt] = (f32x4){0.f, 0.f, 0.f, 0.f};

        for (int ks = 0; ks < 8; ++ks) {
            int row = row0 + w * 16 + l15;
            const float* ap = Asrc + row * 256 + ks * 32 + l4 * 8;
            f16x8 af = cvt8(*(const float4*)ap, *(const float4*)(ap + 4));
            f16x8 bf[4];
            #pragma unroll
            for (int nt = 0; nt < 4; ++nt) {
                if (mode == 1) {
                    int col = col0 + nt * 16 + l15;
                    const float* bp = prot + col * 256 + ks * 32 + l4 * 8;
                    bf[nt] = cvt8(*(const float4*)bp, *(const float4*)(bp + 4));
                } else {
                    bf[nt] = *(const f16x8*)(&Bls[nt * 16 + l15][ks * 32 + l4 * 8]);
                }
            }
            #pragma unroll
            for (int nt = 0; nt < 4; ++nt)
                acc[nt] = __builtin_amdgcn_mfma_f32_16x16x32_f16(af, bf[nt], acc[nt], 0, 0, 0);
        }
        #pragma unroll
        for (int nt = 0; nt < 4; ++nt)
            #pragma unroll
            for (int j = 0; j < 4; ++j) {
                int row = row0 + w * 16 + l4 * 4 + j;
                int col = col0 + nt * 16 + l15;
                float v = acc[nt][j];
                if (mode == 0)      qh16[row * 256 + col] = (_Float16)v;
                else if (mode == 1) sqp[row * 128 + col] = v;
                else                phpk[(((col >> 4) * 2 + ((col >> 3) & 1)) * 128 + row) * 8
                                         + (col & 7)] = (_Float16)(v + b1[col]);
            }
    } else if (b < 217) {
        int chunk = (b - 200) * 256 + t;          // 0..4351
        int ks = chunk >> 8, h = (chunk >> 7) & 1, c = chunk & 127;
        f16x8 o = {};
        if (ks < 16) {
            #pragma unroll
            for (int j = 0; j < 8; ++j)
                o[j] = (_Float16)W2[(ks * 16 + h * 8 + j) * 128 + c];
        } else if (h == 0) {
            o[0] = (_Float16)b2[c];
        }
        w2p[chunk] = o;
    } else if (b < 249) {
        int pid = (b - 217) * 32 + (t >> 3), l8 = t & 7;
        int c = pid >> 6, k = (pid >> 3) & 7, kp = pid & 7;
        const float4* pa = (const float4*)(prot + (c * 8 + k) * 256 + l8 * 32);
        const float4* pb = (const float4*)(prot + (c * 8 + kp) * 256 + l8 * 32);
        float s = 0.f;
        #pragma unroll
        for (int i = 0; i < 8; ++i) {
            float4 x = pa[i], y = pb[i];
            s += x.x * y.x + x.y * y.y + x.z * y.z + x.w * y.w;
        }
        s += __shfl_xor(s, 1); s += __shfl_xor(s, 2); s += __shfl_xor(s, 4);
        if (l8 == 0) Gm[pid] = s;
    } else {
        int m = (b - 249) * 32 + (t >> 3), l8 = t & 7;
        const float4* qp = (const float4*)(query + m * 256 + l8 * 32);
        float s = 0.f;
        #pragma unroll
        for (int i = 0; i < 8; ++i) {
            float4 x = qp[i];
            s += x.x * x.x + x.y * x.y + x.z * x.z + x.w * x.w;
        }
        s += __shfl_xor(s, 1); s += __shfl_xor(s, 2); s += __shfl_xor(s, 4);
        if (l8 == 0) q2[m] = s;
    }
}

// =============== fused4: register-resident K-loop (verbatim round 16 — PASSED, best) ======
__global__ __launch_bounds__(512, 1)
void fused4(const _Float16* __restrict__ qh16,
            const uint4* __restrict__ phpk,
            const uint4* __restrict__ w2p,
            const float* __restrict__ sqp,
            const float* __restrict__ q2,
            const float* __restrict__ Gm,
            const float* __restrict__ W3,
            float* __restrict__ out) {
    __shared__ _Float16 qlds[16 * 256];       // 16 q rows, 8 KB
    __shared__ float w3l[128];
    __shared__ float spart[2][2][4][64];      // [buf][m-sel][cs][ckl] = 4 KB

    int t = threadIdx.x;
    int wid = t >> 6, l = t & 63;
    int rg = wid & 1, cs = wid >> 1;
    int lk = l & 31, h = l >> 5;
    int ch = blockIdx.x & 1;                  // prototype half
    int mg = blockIdx.x >> 1;                 // 0..127
    int ckl = rg * 32 + lk;
    int ck = ch * 64 + ckl;
    int m0 = mg * 16;

    const _Float16* w2h = (const _Float16*)w2p;
    const _Float16* phh = (const _Float16*)phpk;

    // stage 16 q rows (coalesced, one uint4 per thread)
    ((uint4*)qlds)[t] = ((const uint4*)(qh16 + m0 * 256))[t];
    if (t < 128) w3l[t] = W3[t];

    // W2ext strip in regs (m-invariant, 68 VGPR)
    f16x8 wA[17];
    #pragma unroll
    for (int ks = 0; ks < 17; ++ks)
        wA[ks] = *(const f16x8*)(w2h + ((ks * 2 + h) * 128 + cs * 32 + lk) * 8);

    // ph strip in regs (m-invariant, 64 VGPR)
    f16x8 ph[16];
    #pragma unroll
    for (int ks = 0; ks < 16; ++ks)
        ph[ks] = *(const f16x8*)(phh + ((ks * 2 + h) * 128 + ck) * 8);

    __syncthreads();

    for (int mi = 0; mi < 8; ++mi) {
        int mA = m0 + mi * 2;
        const _Float16* qra = qlds + (mi * 2) * 256 + h * 8;
        const _Float16* qrb = qra + 256;

        f32x16 accA = {}, accB = {};

        f16x8 qa[2], qb[2];
        qa[0] = *(const f16x8*)(qra);       qb[0] = *(const f16x8*)(qrb);
        qa[1] = *(const f16x8*)(qra + 16);  qb[1] = *(const f16x8*)(qrb + 16);

        #pragma unroll
        for (int ks = 0; ks < 16; ++ks) {
            f16x8 aA = relu8(qa[ks & 1] + ph[ks]);
            f16x8 aB = relu8(qb[ks & 1] + ph[ks]);
            if (ks < 14) {                    // rolling 2-deep broadcast prefetch
                qa[ks & 1] = *(const f16x8*)(qra + (ks + 2) * 16);
                qb[ks & 1] = *(const f16x8*)(qrb + (ks + 2) * 16);
            }
            accA = __builtin_amdgcn_mfma_f32_32x32x16_f16(wA[ks], aA, accA, 0, 0, 0);
            accB = __builtin_amdgcn_mfma_f32_32x32x16_f16(wA[ks], aB, accB, 0, 0, 0);
        }
        {   // K-extension step: adds b2 (A'ext = b2, B'ext = 1)
            f16x8 e = {};
            if (h == 0) e[0] = (_Float16)1.0f;
            accA = __builtin_amdgcn_mfma_f32_32x32x16_f16(wA[16], e, accA, 0, 0, 0);
            accB = __builtin_amdgcn_mfma_f32_32x32x16_f16(wA[16], e, accB, 0, 0, 0);
        }

        // partial score over this wave's 32 cols; D-row map: cs*32 + (r&3)+8*(r>>2)+4*h
        int buf = mi & 1;
        {
            float s0 = 0.f, s1 = 0.f, s2 = 0.f, s3 = 0.f;
            #pragma unroll
            for (int r = 0; r < 16; r += 4) {
                s0 = fmaf(fmaxf(accA[r + 0], 0.f), w3l[cs * 32 + ((r + 0) & 3) + 8 * ((r + 0) >> 2) + 4 * h], s0);
                s1 = fmaf(fmaxf(accA[r + 1], 0.f), w3l[cs * 32 + ((r + 1) & 3) + 8 * ((r + 1) >> 2) + 4 * h], s1);
                s2 = fmaf(fmaxf(accA[r + 2], 0.f), w3l[cs * 32 + ((r + 2) & 3) + 8 * ((r + 2) >> 2) + 4 * h], s2);
                s3 = fmaf(fmaxf(accA[r + 3], 0.f), w3l[cs * 32 + ((r + 3) & 3) + 8 * ((r + 3) >> 2) + 4 * h], s3);
            }
            float s = (s0 + s1) + (s2 + s3);
            s += __shfl_xor(s, 32);
            if (l < 32) spart[buf][0][cs][ckl] = s;
        }
        {
            float s0 = 0.f, s1 = 0.f, s2 = 0.f, s3 = 0.f;
            #pragma unroll
            for (int r = 0; r < 16; r += 4) {
                s0 = fmaf(fmaxf(accB[r + 0], 0.f), w3l[cs * 32 + ((r + 0) & 3) + 8 * ((r + 0) >> 2) + 4 * h], s0);
                s1 = fmaf(fmaxf(accB[r + 1], 0.f), w3l[cs * 32 + ((r + 1) & 3) + 8 * ((r + 1) >> 2) + 4 * h], s1);
                s2 = fmaf(fmaxf(accB[r + 2], 0.f), w3l[cs * 32 + ((r + 2) & 3) + 8 * ((r + 2) >> 2) + 4 * h], s2);
                s3 = fmaf(fmaxf(accB[r + 3], 0.f), w3l[cs * 32 + ((r + 3) & 3) + 8 * ((r + 3) >> 2) + 4 * h], s3);
            }
            float s = (s0 + s1) + (s2 + s3);
            s += __shfl_xor(s, 32);
            if (l < 32) spart[buf][1][cs][ckl] = s;
        }
        __syncthreads();

        // softmax over K=8 per c + Gram-expanded distance; t<128 covers 2m x 64 ck
        if (t < 128) {
            int msel = t >> 6, cl = t & 63, kk = t & 7;
            int m = mA + msel;
            int cg = ch * 8 + (cl >> 3);
            float s = spart[buf][msel][0][cl] + spart[buf][msel][1][cl]
                    + spart[buf][msel][2][cl] + spart[buf][msel][3][cl];
            float mx = s;
            mx = fmaxf(mx, __shfl_xor(mx, 1));
            mx = fmaxf(mx, __shfl_xor(mx, 2));
            mx = fmaxf(mx, __shfl_xor(mx, 4));
            float e = __expf(s - mx);
            float den = e;
            den += __shfl_xor(den, 1); den += __shfl_xor(den, 2); den += __shfl_xor(den, 4);
            float a = e / den;
            float p2 = a * sqp[m * 128 + ch * 64 + cl];
            float p3 = 0.f;
            #pragma unroll
            for (int kq = 0; kq < 8; ++kq) {
                float ak = __shfl(a, (l & 56) | kq);
                p3 = fmaf(ak, Gm[cg * 64 + kq * 8 + kk], p3);
            }
            p3 *= a;
            float pr = p3 - 2.f * p2;
            pr += __shfl_xor(pr, 1); pr += __shfl_xor(pr, 2); pr += __shfl_xor(pr, 4);
            if (kk == 0)
                out[m * 16 + cg] = -sqrtf(fmaxf(q2[m] + pr, 0.f));
        }
    }
}

extern "C" void kernel_launch(void* const* d_in, const int* in_sizes, int n_in,
                              void* d_out, int out_size, void* d_ws, size_t ws_size,
                              hipStream_t stream) {
    const float* query = (const float*)d_in[0];
    const float* prot  = (const float*)d_in[1];
    const float* W1    = (const float*)d_in[2];
    const float* b1    = (const float*)d_in[3];
    const float* W2    = (const float*)d_in[4];
    const float* b2    = (const float*)d_in[5];
    const float* W3    = (const float*)d_in[6];
    // b3 (d_in[7]): constant pre-softmax shift -> softmax-invariant: unused.

    char* ws = (char*)d_ws;
    _Float16* qh16 = (_Float16*)(ws);                 // 2048*256*2 = 1048576
    f16x8*    w2p  = (f16x8*)(ws + 1048576);          // 4352*16    = 69632
    _Float16* phpk = (_Float16*)(ws + 1118208);       // 128*256*2  = 65536
    float*    sqp  = (float*)(ws + 1183744);          // 2048*128*4 = 1048576
    float*    q2   = (float*)(ws + 2232320);          // 2048*4     = 8192
    float*    Gm   = (float*)(ws + 2240512);          // 1024*4     = 4096
    float* out = (float*)d_out;

    prep1<<<313, 256, 0, stream>>>(query, prot, W1, b1, W2, b2,
                                   qh16, sqp, phpk, w2p, Gm, q2);
    fused4<<<256, 512, 0, stream>>>(qh16, (const uint4*)phpk, (const uint4*)w2p,
                                    sqp, q2, Gm, W3, out);
}